// Round 4
// baseline (208.624 us; speedup 1.0000x reference)
//
#include <hip/hip_runtime.h>
#include <math.h>

#define NN 8192
#define SSEG 32
#define JCH (NN / SSEG)   // 256
#define RHALF (NN / 2)    // 4096

typedef float f8v __attribute__((ext_vector_type(8)));

// ---------------- workspace layout (in floats) ----------------
constexpr size_t OFF_XN   = 0;                                 // [NN][8] normalized rows
constexpr size_t OFF_PNS  = OFF_XN + (size_t)NN * 8;           // [SSEG][NN][8] partial neighbour sums
constexpr size_t OFF_DIF  = OFF_PNS + (size_t)SSEG * NN * 8;   // [NN][8] diffused
constexpr size_t OFF_QS   = OFF_DIF + (size_t)NN * 8;          // [NN][8] q pre-scaled by log2e/sqrt(8)
constexpr size_t OFF_KK   = OFF_QS + (size_t)NN * 8;           // [NN][8] k
constexpr size_t OFF_PACC = OFF_KK + (size_t)NN * 8;           // [SSEG][NN][8] partial attn accum
constexpr size_t OFF_PM   = OFF_PACC + (size_t)SSEG * NN * 8;  // [SSEG][NN] partial max
constexpr size_t OFF_PSUM = OFF_PM + (size_t)SSEG * NN;        // [SSEG][NN] partial sum

// ---------------- kernel 1: row normalize ----------------
__global__ __launch_bounds__(256) void k_norm(const float* __restrict__ in,
                                              float* __restrict__ xn) {
    int r = blockIdx.x * 256 + threadIdx.x;
    const float4* p = reinterpret_cast<const float4*>(in + r * 8);
    float4 a = p[0], b = p[1];
    float ss = a.x*a.x + a.y*a.y + a.z*a.z + a.w*a.w
             + b.x*b.x + b.y*b.y + b.z*b.z + b.w*b.w;
    float inv = 1.0f / (sqrtf(ss) + 1e-12f);
    a.x *= inv; a.y *= inv; a.z *= inv; a.w *= inv;
    b.x *= inv; b.y *= inv; b.z *= inv; b.w *= inv;
    float4* o = reinterpret_cast<float4*>(xn + r * 8);
    o[0] = a; o[1] = b;
}

// ---- kernel 2: adjacency row-sum; lane-rotated coalesced vector loads, 2 rows/thread ----
__global__ __launch_bounds__(256) void k_adj(const float* __restrict__ xn,
                                             const float* __restrict__ in,
                                             float* __restrict__ pns) {
    int tid = threadIdx.x;
    int lane = tid & 63;
    int r0 = blockIdx.x * 256 + tid;     // [0, 4096)
    int r1 = r0 + RHALF;
    int seg = blockIdx.y;
    int j0 = seg * JCH;

    const float4* xp0 = reinterpret_cast<const float4*>(xn + (size_t)r0 * 8);
    float4 xa0 = xp0[0], xb0 = xp0[1];
    const float4* xp1 = reinterpret_cast<const float4*>(xn + (size_t)r1 * 8);
    float4 xa1 = xp1[0], xb1 = xp1[1];

    float A0[8] = {0,0,0,0,0,0,0,0};
    float A1[8] = {0,0,0,0,0,0,0,0};

    for (int c8 = 0; c8 < JCH; c8 += 8) {
        #pragma unroll
        for (int u = 0; u < 8; ++u) {
            int jj = (c8 + u + lane) & (JCH - 1);   // lane-skewed: per-lane distinct, coalesced
            int j = j0 + jj;
            f8v xv = *reinterpret_cast<const f8v*>(xn + (size_t)j * 8);
            float d0 = xa0.x*xv[0] + xa0.y*xv[1] + xa0.z*xv[2] + xa0.w*xv[3]
                     + xb0.x*xv[4] + xb0.y*xv[5] + xb0.z*xv[6] + xb0.w*xv[7];
            float d1 = xa1.x*xv[0] + xa1.y*xv[1] + xa1.z*xv[2] + xa1.w*xv[3]
                     + xb1.x*xv[4] + xb1.y*xv[5] + xb1.z*xv[6] + xb1.w*xv[7];
            float fid0 = d0 * d0;
            float fid1 = d1 * d1;
            if (fid0 >= 0.8f && j != r0) {
                f8v iv = *reinterpret_cast<const f8v*>(in + (size_t)j * 8);
                #pragma unroll
                for (int e = 0; e < 8; ++e) A0[e] += iv[e];
            }
            if (fid1 >= 0.8f && j != r1) {
                f8v iv = *reinterpret_cast<const f8v*>(in + (size_t)j * 8);
                #pragma unroll
                for (int e = 0; e < 8; ++e) A1[e] += iv[e];
            }
        }
    }
    float4* o0 = reinterpret_cast<float4*>(pns + ((size_t)seg * NN + r0) * 8);
    o0[0] = make_float4(A0[0], A0[1], A0[2], A0[3]);
    o0[1] = make_float4(A0[4], A0[5], A0[6], A0[7]);
    float4* o1 = reinterpret_cast<float4*>(pns + ((size_t)seg * NN + r1) * 8);
    o1[0] = make_float4(A1[0], A1[1], A1[2], A1[3]);
    o1[1] = make_float4(A1[4], A1[5], A1[6], A1[7]);
}

// ---- kernel 3: reduce partials, GNN linear+relu, q/k projections (unchanged) ----
__global__ __launch_bounds__(256) void k_diff(const float* __restrict__ pns,
                                              const float* __restrict__ gw,
                                              const float* __restrict__ gb,
                                              const float* __restrict__ rot,
                                              const float* __restrict__ ent,
                                              float* __restrict__ dif,
                                              float* __restrict__ qsb,
                                              float* __restrict__ kkb) {
    int r = blockIdx.x * 256 + threadIdx.x;
    float ns[8] = {0,0,0,0,0,0,0,0};
    for (int s = 0; s < SSEG; ++s) {
        const float4* p = reinterpret_cast<const float4*>(pns + ((size_t)s * NN + r) * 8);
        float4 a = p[0], b = p[1];
        ns[0]+=a.x; ns[1]+=a.y; ns[2]+=a.z; ns[3]+=a.w;
        ns[4]+=b.x; ns[5]+=b.y; ns[6]+=b.z; ns[7]+=b.w;
    }
    float df[8];
    #pragma unroll
    for (int d = 0; d < 8; ++d) {
        float v = gb[d];
        #pragma unroll
        for (int e = 0; e < 8; ++e) v += ns[e] * gw[d * 8 + e];
        df[d] = fmaxf(v, 0.0f);
    }
    const float QSC = (float)(1.4426950408889634 / 2.8284271247461903); // log2(e)/sqrt(8)
    #pragma unroll
    for (int d = 0; d < 8; ++d) {
        float vq = 0.0f, vk = 0.0f;
        #pragma unroll
        for (int e = 0; e < 8; ++e) {
            vq += df[e] * rot[e * 8 + d];
            vk += df[e] * ent[e * 8 + d];
        }
        qsb[r * 8 + d] = vq * QSC;
        kkb[r * 8 + d] = vk;
    }
    float4* o = reinterpret_cast<float4*>(dif + r * 8);
    o[0] = make_float4(df[0], df[1], df[2], df[3]);
    o[1] = make_float4(df[4], df[5], df[6], df[7]);
}

// ---- kernel 4: chunked-flash attention; lane-rotated coalesced vector loads, 2 rows/thread ----
__global__ __launch_bounds__(256) void k_attn(const float* __restrict__ qsb,
                                              const float* __restrict__ kkb,
                                              const float* __restrict__ dif,
                                              float* __restrict__ pacc,
                                              float* __restrict__ pm,
                                              float* __restrict__ psum) {
    int tid = threadIdx.x;
    int lane = tid & 63;
    int r0 = blockIdx.x * 256 + tid;     // [0, 4096)
    int r1 = r0 + RHALF;
    int seg = blockIdx.y;
    int j0 = seg * JCH;

    const float4* qp0 = reinterpret_cast<const float4*>(qsb + (size_t)r0 * 8);
    float4 qa0 = qp0[0], qb0 = qp0[1];
    const float4* qp1 = reinterpret_cast<const float4*>(qsb + (size_t)r1 * 8);
    float4 qa1 = qp1[0], qb1 = qp1[1];

    float m0 = -__builtin_huge_valf(), m1 = -__builtin_huge_valf();
    float sum0 = 0.0f, sum1 = 0.0f;
    float A0[8] = {0,0,0,0,0,0,0,0};
    float A1[8] = {0,0,0,0,0,0,0,0};

    for (int c8 = 0; c8 < JCH; c8 += 8) {
        float s0[8], s1[8];
        f8v dvs[8];
        #pragma unroll
        for (int u = 0; u < 8; ++u) {
            int jj = (c8 + u + lane) & (JCH - 1);
            int j = j0 + jj;
            f8v kv = *reinterpret_cast<const f8v*>(kkb + (size_t)j * 8);
            dvs[u] = *reinterpret_cast<const f8v*>(dif + (size_t)j * 8);
            s0[u] = qa0.x*kv[0] + qa0.y*kv[1] + qa0.z*kv[2] + qa0.w*kv[3]
                  + qb0.x*kv[4] + qb0.y*kv[5] + qb0.z*kv[6] + qb0.w*kv[7];
            s1[u] = qa1.x*kv[0] + qa1.y*kv[1] + qa1.z*kv[2] + qa1.w*kv[3]
                  + qb1.x*kv[4] + qb1.y*kv[5] + qb1.z*kv[6] + qb1.w*kv[7];
        }
        // chunk tree-max per row
        float cm0 = fmaxf(fmaxf(fmaxf(s0[0], s0[1]), fmaxf(s0[2], s0[3])),
                          fmaxf(fmaxf(s0[4], s0[5]), fmaxf(s0[6], s0[7])));
        float cm1 = fmaxf(fmaxf(fmaxf(s1[0], s1[1]), fmaxf(s1[2], s1[3])),
                          fmaxf(fmaxf(s1[4], s1[5]), fmaxf(s1[6], s1[7])));
        // branchless rescale (first chunk: exp2(-inf)=0)
        float mn0 = fmaxf(m0, cm0); float rs0 = exp2f(m0 - mn0); m0 = mn0;
        float mn1 = fmaxf(m1, cm1); float rs1 = exp2f(m1 - mn1); m1 = mn1;
        sum0 *= rs0; sum1 *= rs1;
        #pragma unroll
        for (int e = 0; e < 8; ++e) { A0[e] *= rs0; A1[e] *= rs1; }
        #pragma unroll
        for (int u = 0; u < 8; ++u) {
            float p0 = exp2f(s0[u] - m0);
            float p1 = exp2f(s1[u] - m1);
            sum0 += p0; sum1 += p1;
            #pragma unroll
            for (int e = 0; e < 8; ++e) { A0[e] += p0 * dvs[u][e]; A1[e] += p1 * dvs[u][e]; }
        }
    }

    size_t b0 = (size_t)seg * NN + r0;
    size_t b1 = (size_t)seg * NN + r1;
    float4* o0 = reinterpret_cast<float4*>(pacc + b0 * 8);
    o0[0] = make_float4(A0[0], A0[1], A0[2], A0[3]);
    o0[1] = make_float4(A0[4], A0[5], A0[6], A0[7]);
    float4* o1 = reinterpret_cast<float4*>(pacc + b1 * 8);
    o1[0] = make_float4(A1[0], A1[1], A1[2], A1[3]);
    o1[1] = make_float4(A1[4], A1[5], A1[6], A1[7]);
    pm[b0] = m0;  pm[b1] = m1;
    psum[b0] = sum0; psum[b1] = sum1;
}

// ---- kernel 5: merge attention partials + QCNN stack (unchanged) ----
__global__ __launch_bounds__(256) void k_merge(const float* __restrict__ pacc,
                                               const float* __restrict__ pm,
                                               const float* __restrict__ psum,
                                               const float* __restrict__ qw0, const float* __restrict__ qb0,
                                               const float* __restrict__ qw1, const float* __restrict__ qb1,
                                               const float* __restrict__ qw2, const float* __restrict__ qb2,
                                               const float* __restrict__ qw3, const float* __restrict__ qb3,
                                               const float* __restrict__ qw4, const float* __restrict__ qb4,
                                               const float* __restrict__ qw5, const float* __restrict__ qb5,
                                               float* __restrict__ out) {
    int r = blockIdx.x * 256 + threadIdx.x;
    float M = -__builtin_huge_valf();
    for (int s = 0; s < SSEG; ++s) M = fmaxf(M, pm[(size_t)s * NN + r]);
    float T = 0.0f;
    float A[8] = {0,0,0,0,0,0,0,0};
    for (int s = 0; s < SSEG; ++s) {
        size_t base = (size_t)s * NN + r;
        float c = exp2f(pm[base] - M);
        T += psum[base] * c;
        const float4* p = reinterpret_cast<const float4*>(pacc + base * 8);
        float4 a = p[0], b = p[1];
        A[0]+=c*a.x; A[1]+=c*a.y; A[2]+=c*a.z; A[3]+=c*a.w;
        A[4]+=c*b.x; A[5]+=c*b.y; A[6]+=c*b.z; A[7]+=c*b.w;
    }
    float invT = 1.0f / T;
    float h0[8];
    #pragma unroll
    for (int d = 0; d < 8; ++d) h0[d] = A[d] * invT;

    float h1[16];
    #pragma unroll
    for (int t = 0; t < 16; ++t) {
        float v = qb0[t];
        #pragma unroll
        for (int e = 0; e < 8; ++e) v += h0[e] * qw0[t * 8 + e];
        h1[t] = tanhf(v);
    }
    float h2[16];
    #pragma unroll
    for (int t = 0; t < 16; ++t) {
        float v = qb1[t];
        #pragma unroll
        for (int e = 0; e < 16; ++e) v += h1[e] * qw1[t * 16 + e];
        h2[t] = tanhf(v);
    }
    float h3[12];
    #pragma unroll
    for (int t = 0; t < 12; ++t) {
        float v = qb2[t];
        #pragma unroll
        for (int e = 0; e < 16; ++e) v += h2[e] * qw2[t * 16 + e];
        h3[t] = tanhf(v);
    }
    float h4[8];
    #pragma unroll
    for (int t = 0; t < 8; ++t) {
        float v = qb3[t];
        #pragma unroll
        for (int e = 0; e < 12; ++e) v += h3[e] * qw3[t * 12 + e];
        h4[t] = tanhf(v);
    }
    float h5[4];
    #pragma unroll
    for (int t = 0; t < 4; ++t) {
        float v = qb4[t];
        #pragma unroll
        for (int e = 0; e < 8; ++e) v += h4[e] * qw4[t * 8 + e];
        h5[t] = tanhf(v);
    }
    float o = qb5[0];
    #pragma unroll
    for (int e = 0; e < 4; ++e) o += h5[e] * qw5[e];
    out[r] = 1.0f / (1.0f + expf(-o));
}

extern "C" void kernel_launch(void* const* d_in, const int* in_sizes, int n_in,
                              void* d_out, int out_size, void* d_ws, size_t ws_size,
                              hipStream_t stream) {
    const float* in  = (const float*)d_in[0];
    const float* rot = (const float*)d_in[1];
    const float* ent = (const float*)d_in[2];
    const float* gw  = (const float*)d_in[3];
    const float* gb  = (const float*)d_in[4];
    const float* qw0 = (const float*)d_in[5];
    const float* qb0 = (const float*)d_in[6];
    const float* qw1 = (const float*)d_in[7];
    const float* qb1 = (const float*)d_in[8];
    const float* qw2 = (const float*)d_in[9];
    const float* qb2 = (const float*)d_in[10];
    const float* qw3 = (const float*)d_in[11];
    const float* qb3 = (const float*)d_in[12];
    const float* qw4 = (const float*)d_in[13];
    const float* qb4 = (const float*)d_in[14];
    const float* qw5 = (const float*)d_in[15];
    const float* qb5 = (const float*)d_in[16];

    float* ws   = (float*)d_ws;
    float* xn   = ws + OFF_XN;
    float* pns  = ws + OFF_PNS;
    float* dif  = ws + OFF_DIF;
    float* qsb  = ws + OFF_QS;
    float* kkb  = ws + OFF_KK;
    float* pacc = ws + OFF_PACC;
    float* pm   = ws + OFF_PM;
    float* psum = ws + OFF_PSUM;

    dim3 blk(256);
    k_norm<<<dim3(NN / 256), blk, 0, stream>>>(in, xn);
    k_adj<<<dim3(RHALF / 256, SSEG), blk, 0, stream>>>(xn, in, pns);
    k_diff<<<dim3(NN / 256), blk, 0, stream>>>(pns, gw, gb, rot, ent, dif, qsb, kkb);
    k_attn<<<dim3(RHALF / 256, SSEG), blk, 0, stream>>>(qsb, kkb, dif, pacc, pm, psum);
    k_merge<<<dim3(NN / 256), blk, 0, stream>>>(pacc, pm, psum,
                                                qw0, qb0, qw1, qb1, qw2, qb2,
                                                qw3, qb3, qw4, qb4, qw5, qb5,
                                                (float*)d_out);
}

// Round 5
// 131.367 us; speedup vs baseline: 1.5881x; 1.5881x over previous
//
#include <hip/hip_runtime.h>
#include <math.h>

#define NN 8192
#define SSEG 32
#define JCH (NN / SSEG)   // 256
#define RHALF (NN / 2)    // 4096

typedef float f8v __attribute__((ext_vector_type(8)));

// ---------------- workspace layout (in floats) ----------------
constexpr size_t OFF_XN   = 0;                                 // [NN][8] normalized rows
constexpr size_t OFF_PNS  = OFF_XN + (size_t)NN * 8;           // [SSEG][NN][8] partial neighbour sums
constexpr size_t OFF_DIF  = OFF_PNS + (size_t)SSEG * NN * 8;   // [NN][8] diffused
constexpr size_t OFF_QS   = OFF_DIF + (size_t)NN * 8;          // [NN][8] q pre-scaled by log2e/sqrt(8)
constexpr size_t OFF_KK   = OFF_QS + (size_t)NN * 8;           // [NN][8] k
constexpr size_t OFF_PACC = OFF_KK + (size_t)NN * 8;           // [SSEG][NN][8] partial attn accum
constexpr size_t OFF_PM   = OFF_PACC + (size_t)SSEG * NN * 8;  // [SSEG][NN] partial max
constexpr size_t OFF_PSUM = OFF_PM + (size_t)SSEG * NN;        // [SSEG][NN] partial sum

// ---------------- kernel 1: row normalize ----------------
__global__ __launch_bounds__(256) void k_norm(const float* __restrict__ in,
                                              float* __restrict__ xn) {
    int r = blockIdx.x * 256 + threadIdx.x;
    const float4* p = reinterpret_cast<const float4*>(in + r * 8);
    float4 a = p[0], b = p[1];
    float ss = a.x*a.x + a.y*a.y + a.z*a.z + a.w*a.w
             + b.x*b.x + b.y*b.y + b.z*b.z + b.w*b.w;
    float inv = 1.0f / (sqrtf(ss) + 1e-12f);
    a.x *= inv; a.y *= inv; a.z *= inv; a.w *= inv;
    b.x *= inv; b.y *= inv; b.z *= inv; b.w *= inv;
    float4* o = reinterpret_cast<float4*>(xn + r * 8);
    o[0] = a; o[1] = b;
}

// ---- kernel 2: adjacency row-sum; LDS broadcast (conflict-free staging), 2 rows/thread ----
__global__ __launch_bounds__(256) void k_adj(const float* __restrict__ xn,
                                             const float* __restrict__ in,
                                             float* __restrict__ pns) {
    __shared__ float4 sx[JCH * 2];   // 8 KB: segment's normalized rows
    int tid = threadIdx.x;
    int r0 = blockIdx.x * 256 + tid;     // [0, 4096)
    int r1 = r0 + RHALF;
    int seg = blockIdx.y;
    int j0 = seg * JCH;

    // conflict-free stage: lane-consecutive float4 writes
    {
        const float4* src = reinterpret_cast<const float4*>(xn + (size_t)j0 * 8);
        sx[tid]       = src[tid];
        sx[tid + 256] = src[tid + 256];
    }
    const float4* xp0 = reinterpret_cast<const float4*>(xn + (size_t)r0 * 8);
    float4 xa0 = xp0[0], xb0 = xp0[1];
    const float4* xp1 = reinterpret_cast<const float4*>(xn + (size_t)r1 * 8);
    float4 xa1 = xp1[0], xb1 = xp1[1];
    __syncthreads();

    float A0[8] = {0,0,0,0,0,0,0,0};
    float A1[8] = {0,0,0,0,0,0,0,0};

    for (int c8 = 0; c8 < JCH; c8 += 8) {
        #pragma unroll
        for (int u = 0; u < 8; ++u) {
            int t = c8 + u;
            int j = j0 + t;
            float4 a = sx[t * 2], b = sx[t * 2 + 1];   // uniform broadcast reads
            float d0 = xa0.x*a.x + xa0.y*a.y + xa0.z*a.z + xa0.w*a.w
                     + xb0.x*b.x + xb0.y*b.y + xb0.z*b.z + xb0.w*b.w;
            float d1 = xa1.x*a.x + xa1.y*a.y + xa1.z*a.z + xa1.w*a.w
                     + xb1.x*b.x + xb1.y*b.y + xb1.z*b.z + xb1.w*b.w;
            bool h0 = (d0 * d0 >= 0.8f) && (j != r0);
            bool h1 = (d1 * d1 >= 0.8f) && (j != r1);
            if (h0 || h1) {                            // rare: exec-masked global load
                f8v iv = *reinterpret_cast<const f8v*>(in + (size_t)j * 8);
                if (h0) {
                    #pragma unroll
                    for (int e = 0; e < 8; ++e) A0[e] += iv[e];
                }
                if (h1) {
                    #pragma unroll
                    for (int e = 0; e < 8; ++e) A1[e] += iv[e];
                }
            }
        }
    }
    float4* o0 = reinterpret_cast<float4*>(pns + ((size_t)seg * NN + r0) * 8);
    o0[0] = make_float4(A0[0], A0[1], A0[2], A0[3]);
    o0[1] = make_float4(A0[4], A0[5], A0[6], A0[7]);
    float4* o1 = reinterpret_cast<float4*>(pns + ((size_t)seg * NN + r1) * 8);
    o1[0] = make_float4(A1[0], A1[1], A1[2], A1[3]);
    o1[1] = make_float4(A1[4], A1[5], A1[6], A1[7]);
}

// ---- kernel 3: reduce partials, GNN linear+relu, q/k projections (unchanged) ----
__global__ __launch_bounds__(256) void k_diff(const float* __restrict__ pns,
                                              const float* __restrict__ gw,
                                              const float* __restrict__ gb,
                                              const float* __restrict__ rot,
                                              const float* __restrict__ ent,
                                              float* __restrict__ dif,
                                              float* __restrict__ qsb,
                                              float* __restrict__ kkb) {
    int r = blockIdx.x * 256 + threadIdx.x;
    float ns[8] = {0,0,0,0,0,0,0,0};
    for (int s = 0; s < SSEG; ++s) {
        const float4* p = reinterpret_cast<const float4*>(pns + ((size_t)s * NN + r) * 8);
        float4 a = p[0], b = p[1];
        ns[0]+=a.x; ns[1]+=a.y; ns[2]+=a.z; ns[3]+=a.w;
        ns[4]+=b.x; ns[5]+=b.y; ns[6]+=b.z; ns[7]+=b.w;
    }
    float df[8];
    #pragma unroll
    for (int d = 0; d < 8; ++d) {
        float v = gb[d];
        #pragma unroll
        for (int e = 0; e < 8; ++e) v += ns[e] * gw[d * 8 + e];
        df[d] = fmaxf(v, 0.0f);
    }
    const float QSC = (float)(1.4426950408889634 / 2.8284271247461903); // log2(e)/sqrt(8)
    #pragma unroll
    for (int d = 0; d < 8; ++d) {
        float vq = 0.0f, vk = 0.0f;
        #pragma unroll
        for (int e = 0; e < 8; ++e) {
            vq += df[e] * rot[e * 8 + d];
            vk += df[e] * ent[e * 8 + d];
        }
        qsb[r * 8 + d] = vq * QSC;
        kkb[r * 8 + d] = vk;
    }
    float4* o = reinterpret_cast<float4*>(dif + r * 8);
    o[0] = make_float4(df[0], df[1], df[2], df[3]);
    o[1] = make_float4(df[4], df[5], df[6], df[7]);
}

// ---- kernel 4: chunked-flash attention; LDS broadcast (conflict-free staging), 2 rows/thread ----
__global__ __launch_bounds__(256) void k_attn(const float* __restrict__ qsb,
                                              const float* __restrict__ kkb,
                                              const float* __restrict__ dif,
                                              float* __restrict__ pacc,
                                              float* __restrict__ pm,
                                              float* __restrict__ psum) {
    __shared__ float4 sk[JCH * 2];   // 8 KB: k rows
    __shared__ float4 sd[JCH * 2];   // 8 KB: dif rows
    int tid = threadIdx.x;
    int r0 = blockIdx.x * 256 + tid;     // [0, 4096)
    int r1 = r0 + RHALF;
    int seg = blockIdx.y;
    int j0 = seg * JCH;

    {
        const float4* ksrc = reinterpret_cast<const float4*>(kkb + (size_t)j0 * 8);
        sk[tid]       = ksrc[tid];
        sk[tid + 256] = ksrc[tid + 256];
        const float4* dsrc = reinterpret_cast<const float4*>(dif + (size_t)j0 * 8);
        sd[tid]       = dsrc[tid];
        sd[tid + 256] = dsrc[tid + 256];
    }
    const float4* qp0 = reinterpret_cast<const float4*>(qsb + (size_t)r0 * 8);
    float4 qa0 = qp0[0], qb0 = qp0[1];
    const float4* qp1 = reinterpret_cast<const float4*>(qsb + (size_t)r1 * 8);
    float4 qa1 = qp1[0], qb1 = qp1[1];
    __syncthreads();

    float m0 = -__builtin_huge_valf(), m1 = -__builtin_huge_valf();
    float sum0 = 0.0f, sum1 = 0.0f;
    float A0[8] = {0,0,0,0,0,0,0,0};
    float A1[8] = {0,0,0,0,0,0,0,0};

    for (int c8 = 0; c8 < JCH; c8 += 8) {
        float s0[8], s1[8];
        #pragma unroll
        for (int u = 0; u < 8; ++u) {
            int t = c8 + u;
            float4 ka = sk[t * 2], kb = sk[t * 2 + 1];   // uniform broadcast
            s0[u] = qa0.x*ka.x + qa0.y*ka.y + qa0.z*ka.z + qa0.w*ka.w
                  + qb0.x*kb.x + qb0.y*kb.y + qb0.z*kb.z + qb0.w*kb.w;
            s1[u] = qa1.x*ka.x + qa1.y*ka.y + qa1.z*ka.z + qa1.w*ka.w
                  + qb1.x*kb.x + qb1.y*kb.y + qb1.z*kb.z + qb1.w*kb.w;
        }
        // chunk tree-max per row
        float cm0 = fmaxf(fmaxf(fmaxf(s0[0], s0[1]), fmaxf(s0[2], s0[3])),
                          fmaxf(fmaxf(s0[4], s0[5]), fmaxf(s0[6], s0[7])));
        float cm1 = fmaxf(fmaxf(fmaxf(s1[0], s1[1]), fmaxf(s1[2], s1[3])),
                          fmaxf(fmaxf(s1[4], s1[5]), fmaxf(s1[6], s1[7])));
        // branchless rescale (first chunk: exp2(-inf)=0)
        float mn0 = fmaxf(m0, cm0); float rs0 = exp2f(m0 - mn0); m0 = mn0;
        float mn1 = fmaxf(m1, cm1); float rs1 = exp2f(m1 - mn1); m1 = mn1;
        sum0 *= rs0; sum1 *= rs1;
        #pragma unroll
        for (int e = 0; e < 8; ++e) { A0[e] *= rs0; A1[e] *= rs1; }
        #pragma unroll
        for (int u = 0; u < 8; ++u) {
            int t = c8 + u;
            float4 da = sd[t * 2], db = sd[t * 2 + 1];   // uniform broadcast
            float p0 = exp2f(s0[u] - m0);
            float p1 = exp2f(s1[u] - m1);
            sum0 += p0; sum1 += p1;
            A0[0] += p0*da.x; A0[1] += p0*da.y; A0[2] += p0*da.z; A0[3] += p0*da.w;
            A0[4] += p0*db.x; A0[5] += p0*db.y; A0[6] += p0*db.z; A0[7] += p0*db.w;
            A1[0] += p1*da.x; A1[1] += p1*da.y; A1[2] += p1*da.z; A1[3] += p1*da.w;
            A1[4] += p1*db.x; A1[5] += p1*db.y; A1[6] += p1*db.z; A1[7] += p1*db.w;
        }
    }

    size_t b0 = (size_t)seg * NN + r0;
    size_t b1 = (size_t)seg * NN + r1;
    float4* o0 = reinterpret_cast<float4*>(pacc + b0 * 8);
    o0[0] = make_float4(A0[0], A0[1], A0[2], A0[3]);
    o0[1] = make_float4(A0[4], A0[5], A0[6], A0[7]);
    float4* o1 = reinterpret_cast<float4*>(pacc + b1 * 8);
    o1[0] = make_float4(A1[0], A1[1], A1[2], A1[3]);
    o1[1] = make_float4(A1[4], A1[5], A1[6], A1[7]);
    pm[b0] = m0;  pm[b1] = m1;
    psum[b0] = sum0; psum[b1] = sum1;
}

// ---- kernel 5: merge attention partials + QCNN stack (unchanged) ----
__global__ __launch_bounds__(256) void k_merge(const float* __restrict__ pacc,
                                               const float* __restrict__ pm,
                                               const float* __restrict__ psum,
                                               const float* __restrict__ qw0, const float* __restrict__ qb0,
                                               const float* __restrict__ qw1, const float* __restrict__ qb1,
                                               const float* __restrict__ qw2, const float* __restrict__ qb2,
                                               const float* __restrict__ qw3, const float* __restrict__ qb3,
                                               const float* __restrict__ qw4, const float* __restrict__ qb4,
                                               const float* __restrict__ qw5, const float* __restrict__ qb5,
                                               float* __restrict__ out) {
    int r = blockIdx.x * 256 + threadIdx.x;
    float M = -__builtin_huge_valf();
    for (int s = 0; s < SSEG; ++s) M = fmaxf(M, pm[(size_t)s * NN + r]);
    float T = 0.0f;
    float A[8] = {0,0,0,0,0,0,0,0};
    for (int s = 0; s < SSEG; ++s) {
        size_t base = (size_t)s * NN + r;
        float c = exp2f(pm[base] - M);
        T += psum[base] * c;
        const float4* p = reinterpret_cast<const float4*>(pacc + base * 8);
        float4 a = p[0], b = p[1];
        A[0]+=c*a.x; A[1]+=c*a.y; A[2]+=c*a.z; A[3]+=c*a.w;
        A[4]+=c*b.x; A[5]+=c*b.y; A[6]+=c*b.z; A[7]+=c*b.w;
    }
    float invT = 1.0f / T;
    float h0[8];
    #pragma unroll
    for (int d = 0; d < 8; ++d) h0[d] = A[d] * invT;

    float h1[16];
    #pragma unroll
    for (int t = 0; t < 16; ++t) {
        float v = qb0[t];
        #pragma unroll
        for (int e = 0; e < 8; ++e) v += h0[e] * qw0[t * 8 + e];
        h1[t] = tanhf(v);
    }
    float h2[16];
    #pragma unroll
    for (int t = 0; t < 16; ++t) {
        float v = qb1[t];
        #pragma unroll
        for (int e = 0; e < 16; ++e) v += h1[e] * qw1[t * 16 + e];
        h2[t] = tanhf(v);
    }
    float h3[12];
    #pragma unroll
    for (int t = 0; t < 12; ++t) {
        float v = qb2[t];
        #pragma unroll
        for (int e = 0; e < 16; ++e) v += h2[e] * qw2[t * 16 + e];
        h3[t] = tanhf(v);
    }
    float h4[8];
    #pragma unroll
    for (int t = 0; t < 8; ++t) {
        float v = qb3[t];
        #pragma unroll
        for (int e = 0; e < 12; ++e) v += h3[e] * qw3[t * 12 + e];
        h4[t] = tanhf(v);
    }
    float h5[4];
    #pragma unroll
    for (int t = 0; t < 4; ++t) {
        float v = qb4[t];
        #pragma unroll
        for (int e = 0; e < 8; ++e) v += h4[e] * qw4[t * 8 + e];
        h5[t] = tanhf(v);
    }
    float o = qb5[0];
    #pragma unroll
    for (int e = 0; e < 4; ++e) o += h5[e] * qw5[e];
    out[r] = 1.0f / (1.0f + expf(-o));
}

extern "C" void kernel_launch(void* const* d_in, const int* in_sizes, int n_in,
                              void* d_out, int out_size, void* d_ws, size_t ws_size,
                              hipStream_t stream) {
    const float* in  = (const float*)d_in[0];
    const float* rot = (const float*)d_in[1];
    const float* ent = (const float*)d_in[2];
    const float* gw  = (const float*)d_in[3];
    const float* gb  = (const float*)d_in[4];
    const float* qw0 = (const float*)d_in[5];
    const float* qb0 = (const float*)d_in[6];
    const float* qw1 = (const float*)d_in[7];
    const float* qb1 = (const float*)d_in[8];
    const float* qw2 = (const float*)d_in[9];
    const float* qb2 = (const float*)d_in[10];
    const float* qw3 = (const float*)d_in[11];
    const float* qb3 = (const float*)d_in[12];
    const float* qw4 = (const float*)d_in[13];
    const float* qb4 = (const float*)d_in[14];
    const float* qw5 = (const float*)d_in[15];
    const float* qb5 = (const float*)d_in[16];

    float* ws   = (float*)d_ws;
    float* xn   = ws + OFF_XN;
    float* pns  = ws + OFF_PNS;
    float* dif  = ws + OFF_DIF;
    float* qsb  = ws + OFF_QS;
    float* kkb  = ws + OFF_KK;
    float* pacc = ws + OFF_PACC;
    float* pm   = ws + OFF_PM;
    float* psum = ws + OFF_PSUM;

    dim3 blk(256);
    k_norm<<<dim3(NN / 256), blk, 0, stream>>>(in, xn);
    k_adj<<<dim3(RHALF / 256, SSEG), blk, 0, stream>>>(xn, in, pns);
    k_diff<<<dim3(NN / 256), blk, 0, stream>>>(pns, gw, gb, rot, ent, dif, qsb, kkb);
    k_attn<<<dim3(RHALF / 256, SSEG), blk, 0, stream>>>(qsb, kkb, dif, pacc, pm, psum);
    k_merge<<<dim3(NN / 256), blk, 0, stream>>>(pacc, pm, psum,
                                                qw0, qb0, qw1, qb1, qw2, qb2,
                                                qw3, qb3, qw4, qb4, qw5, qb5,
                                                (float*)d_out);
}